// Round 1
// baseline (1755.770 us; speedup 1.0000x reference)
//
#include <hip/hip_runtime.h>
#include <stdint.h>

// CombinedLoss: weighted CE + dice + focal + connected-component separation.
// B=16, C=3, H=W=512. Output: single f32 scalar.
//
// Pipeline:
//   k_main    : fused softmax losses + bit-packed fg masks (pred read ONCE)
//   k_labinit : masks -> union-find label init + aux (min/max) init + fg counts
//   k_merge   : one-pass union-find over 8-connectivity edges (atomicMin link)
//   k_flatten : path-compress labels to roots
//   k_scatter : per overlap pixel: atomicMax/Min of opposite-root into key-root slot
//   k_count   : per root: distinct-count>1  => penalty++
//   k_final   : combine everything into d_out[0]

#define NB 16
#define NC 3
#define HH 512
#define WW 512
#define HW (HH * WW)          // 262144
#define NPIX (NB * HW)        // 4194304
#define LOG2_HW 18
#define IGNORE_IDX 255
#define SCALE_IDX 2

struct Accum {
  double ce_num, ce_den, focal_num;
  unsigned long long valid_pix;
  double sum_probs[NB * NC];
  double inter[NB * NC];
  unsigned long long cls_cnt[NB * NC];
  int tcount[NB];
  int pcount[NB];
  int pen[NB];
};

__device__ __forceinline__ double wredd(double v) {
#pragma unroll
  for (int o = 32; o > 0; o >>= 1) v += __shfl_down(v, o, 64);
  return v;
}
__device__ __forceinline__ unsigned int wredu(unsigned int v) {
#pragma unroll
  for (int o = 32; o > 0; o >>= 1) v += __shfl_down(v, o, 64);
  return v;
}

// ---------- fused pointwise losses + mask generation ----------
__global__ __launch_bounds__(256) void k_main(
    const float* __restrict__ pred, const int* __restrict__ tgt,
    const float* __restrict__ cw, Accum* __restrict__ acc,
    unsigned long long* __restrict__ tmask, unsigned long long* __restrict__ pmask) {
  const int bid = blockIdx.x;
  const int b = bid >> 6;        // 64 blocks per batch image
  const int chunk = bid & 63;    // 4096 pixels per block, 16 iters of 256
  const int tid = threadIdx.x;
  const float w0 = cw[0], w1 = cw[1], w2 = cw[2];
  const float* __restrict__ pb = pred + (size_t)b * NC * HW;

  double ce_num = 0.0, ce_den = 0.0, focal = 0.0;
  double sp0 = 0, sp1 = 0, sp2 = 0, it0 = 0, it1 = 0, it2 = 0;
  unsigned int c0 = 0, c1 = 0, c2 = 0, vc = 0;

#pragma unroll 1
  for (int k = 0; k < 16; ++k) {
    const int i = (chunk << 12) + (k << 8) + tid;  // local pixel in batch
    const int gp = (b << LOG2_HW) + i;
    const float x0 = pb[i];
    const float x1 = pb[i + HW];
    const float x2 = pb[i + 2 * HW];
    const int t = tgt[gp];

    // log_softmax, jax style: (x - max) - log(sum(exp(x - max)))
    const float m = fmaxf(fmaxf(x0, x1), x2);
    const float e0 = expf(x0 - m), e1 = expf(x1 - m), e2 = expf(x2 - m);
    const float s = e0 + e1 + e2;
    const float ls = logf(s);
    const float lp0 = (x0 - m) - ls, lp1 = (x1 - m) - ls, lp2 = (x2 - m) - ls;
    const float p0 = expf(lp0), p1 = expf(lp1), p2 = expf(lp2);  // ref: exp(logp)

    sp0 += (double)p0; sp1 += (double)p1; sp2 += (double)p2;

    const int tc = (t < 0) ? 0 : ((t > NC - 1) ? NC - 1 : t);
    const float lpt = (tc == 0) ? lp0 : ((tc == 1) ? lp1 : lp2);
    const float pt  = (tc == 0) ? p0  : ((tc == 1) ? p1  : p2);
    const float cwt = (tc == 0) ? w0  : ((tc == 1) ? w1  : w2);
    const float valid = (t != IGNORE_IDX) ? 1.0f : 0.0f;
    const float wv = cwt * valid;

    ce_num += (double)(wv * (-lpt));
    ce_den += (double)wv;
    const float om = 1.0f - pt;
    focal += (double)(cwt * om * om * (-lpt) * valid);
    vc += (t != IGNORE_IDX) ? 1u : 0u;

    if (t >= 0 && t < NC) {  // one_hot(out-of-range) == 0
      if (t == 0)      { it0 += (double)p0; c0++; }
      else if (t == 1) { it1 += (double)p1; c1++; }
      else             { it2 += (double)p2; c2++; }
    }

    // binary masks for separation loss (bit-packed, 1 word per wave)
    const bool tb = (t == SCALE_IDX);
    const float p2soft = e2 / s;  // jax.nn.softmax formula
    const bool pbit = (p2soft > 0.5f);
    const unsigned long long mt = __ballot(tb);
    const unsigned long long mp = __ballot(pbit);
    if ((tid & 63) == 0) {
      tmask[gp >> 6] = mt;
      pmask[gp >> 6] = mp;
    }
  }

  // wave -> block -> global reduction (keeps same-address f64 atomics at 1/block)
  __shared__ double sd[4][9];
  __shared__ unsigned int si[4][4];
  const int wvid = tid >> 6, ln = tid & 63;
  const double r0 = wredd(ce_num), r1 = wredd(ce_den), r2 = wredd(focal),
               r3 = wredd(sp0), r4 = wredd(sp1), r5 = wredd(sp2),
               r6 = wredd(it0), r7 = wredd(it1), r8 = wredd(it2);
  const unsigned int u0 = wredu(c0), u1 = wredu(c1), u2 = wredu(c2), u3 = wredu(vc);
  if (ln == 0) {
    sd[wvid][0] = r0; sd[wvid][1] = r1; sd[wvid][2] = r2;
    sd[wvid][3] = r3; sd[wvid][4] = r4; sd[wvid][5] = r5;
    sd[wvid][6] = r6; sd[wvid][7] = r7; sd[wvid][8] = r8;
    si[wvid][0] = u0; si[wvid][1] = u1; si[wvid][2] = u2; si[wvid][3] = u3;
  }
  __syncthreads();
  if (tid == 0) {
    double a[9] = {0, 0, 0, 0, 0, 0, 0, 0, 0};
    unsigned int bsum[4] = {0, 0, 0, 0};
    for (int w = 0; w < 4; ++w) {
      for (int q = 0; q < 9; ++q) a[q] += sd[w][q];
      for (int q = 0; q < 4; ++q) bsum[q] += si[w][q];
    }
    atomicAdd(&acc->ce_num, a[0]);
    atomicAdd(&acc->ce_den, a[1]);
    atomicAdd(&acc->focal_num, a[2]);
    atomicAdd(&acc->sum_probs[b * NC + 0], a[3]);
    atomicAdd(&acc->sum_probs[b * NC + 1], a[4]);
    atomicAdd(&acc->sum_probs[b * NC + 2], a[5]);
    atomicAdd(&acc->inter[b * NC + 0], a[6]);
    atomicAdd(&acc->inter[b * NC + 1], a[7]);
    atomicAdd(&acc->inter[b * NC + 2], a[8]);
    atomicAdd(&acc->cls_cnt[b * NC + 0], (unsigned long long)bsum[0]);
    atomicAdd(&acc->cls_cnt[b * NC + 1], (unsigned long long)bsum[1]);
    atomicAdd(&acc->cls_cnt[b * NC + 2], (unsigned long long)bsum[2]);
    atomicAdd(&acc->valid_pix, (unsigned long long)bsum[3]);
  }
}

// ---------- union-find ----------
__device__ __forceinline__ int lread(int* p) {
  // bypass per-CU L1: other CUs' atomicMin land in L2
  return __hip_atomic_load(p, __ATOMIC_RELAXED, __HIP_MEMORY_SCOPE_AGENT);
}
__device__ __forceinline__ int findroot(int* L, int x) {
  int p = lread(&L[x]);
  while (p != x) { x = p; p = lread(&L[x]); }
  return x;
}
__device__ __forceinline__ void unite(int* L, int a, int b) {
  int la = findroot(L, a);
  int lb = findroot(L, b);
  while (la != lb) {
    if (la < lb) { int t = la; la = lb; lb = t; }  // la > lb
    const int old = atomicMin(&L[la], lb);
    if (old == la) break;  // linked a true root
    la = old;              // la was already linked; continue merging old vs lb
  }
}

__global__ __launch_bounds__(256) void k_labinit(
    const unsigned long long* __restrict__ tmask, const unsigned long long* __restrict__ pmask,
    int* __restrict__ tlab, int* __restrict__ plab,
    int* __restrict__ tmx, int* __restrict__ tmn,
    int* __restrict__ pmx, int* __restrict__ pmn,
    Accum* __restrict__ acc, int b0) {
  const int gt = blockIdx.x * 256 + threadIdx.x;
  const int bb = gt >> LOG2_HW;
  const int i = gt & (HW - 1);
  const int gb = b0 + bb;
  const int widx = ((gb << LOG2_HW) | i) >> 6;
  const unsigned long long wt = tmask[widx];
  const unsigned long long wp = pmask[widx];
  const int lane = i & 63;
  tlab[gt] = ((wt >> lane) & 1ull) ? i : -1;
  plab[gt] = ((wp >> lane) & 1ull) ? i : -1;
  tmx[gt] = -1; tmn[gt] = 0x7fffffff;
  pmx[gt] = -1; pmn[gt] = 0x7fffffff;
  if ((threadIdx.x & 63) == 0) {  // wave's 64 lanes == this word's 64 bits
    atomicAdd(&acc->tcount[gb], (int)__popcll(wt));
    atomicAdd(&acc->pcount[gb], (int)__popcll(wp));
  }
}

__device__ __forceinline__ void merge_px(int* L, int i, int x) {
  if (L[i] < 0) return;
  if (x > 0 && L[i - 1] >= 0) unite(L, i, i - 1);
  if (i >= WW) {
    if (L[i - WW] >= 0) unite(L, i, i - WW);
    if (x > 0 && L[i - WW - 1] >= 0) unite(L, i, i - WW - 1);
    if (x < WW - 1 && L[i - WW + 1] >= 0) unite(L, i, i - WW + 1);
  }
}

__global__ __launch_bounds__(256) void k_merge(int* __restrict__ tlab, int* __restrict__ plab) {
  const int gt = blockIdx.x * 256 + threadIdx.x;
  const int bb = gt >> LOG2_HW;
  const int i = gt & (HW - 1);
  const int x = i & (WW - 1);
  merge_px(tlab + (bb << LOG2_HW), i, x);
  merge_px(plab + (bb << LOG2_HW), i, x);
}

__global__ __launch_bounds__(256) void k_flatten(int* __restrict__ tlab, int* __restrict__ plab) {
  const int gt = blockIdx.x * 256 + threadIdx.x;
  const int bb = gt >> LOG2_HW;
  const int i = gt & (HW - 1);
  int* Lt = tlab + (bb << LOG2_HW);
  if (Lt[i] >= 0) Lt[i] = findroot(Lt, i);
  int* Lp = plab + (bb << LOG2_HW);
  if (Lp[i] >= 0) Lp[i] = findroot(Lp, i);
}

__global__ __launch_bounds__(256) void k_scatter(
    const int* __restrict__ tlab, const int* __restrict__ plab,
    int* __restrict__ tmx, int* __restrict__ tmn,
    int* __restrict__ pmx, int* __restrict__ pmn) {
  const int gt = blockIdx.x * 256 + threadIdx.x;
  const int bb = gt >> LOG2_HW;
  const int tl = tlab[gt];
  const int pl = plab[gt];
  if (tl >= 0 && pl >= 0) {
    const int base = bb << LOG2_HW;
    atomicMax(&tmx[base + tl], pl);
    atomicMin(&tmn[base + tl], pl);
    atomicMax(&pmx[base + pl], tl);
    atomicMin(&pmn[base + pl], tl);
  }
}

__global__ __launch_bounds__(256) void k_count(
    const int* __restrict__ tlab, const int* __restrict__ plab,
    const int* __restrict__ tmx, const int* __restrict__ tmn,
    const int* __restrict__ pmx, const int* __restrict__ pmn,
    Accum* __restrict__ acc, int b0) {
  const int gt = blockIdx.x * 256 + threadIdx.x;
  const int bb = gt >> LOG2_HW;
  const int i = gt & (HW - 1);
  int add = 0;
  if (tlab[gt] == i) {  // target-component root
    const int mx = tmx[gt];
    if (mx >= 0 && mx != tmn[gt]) add++;
  }
  if (plab[gt] == i) {  // pred-component root
    const int mx = pmx[gt];
    if (mx >= 0 && mx != pmn[gt]) add++;
  }
  if (add) atomicAdd(&acc->pen[b0 + bb], add);
}

__global__ void k_final(const Accum* __restrict__ acc, float* __restrict__ out) {
  if (threadIdx.x != 0 || blockIdx.x != 0) return;
  const double ce = acc->ce_num / acc->ce_den;
  double dsum = 0.0;
  for (int k = 0; k < NB * NC; ++k) {
    const double un = acc->sum_probs[k] + (double)acc->cls_cnt[k];
    dsum += (2.0 * acc->inter[k] + 1e-6) / (un + 1e-6);
  }
  const double dice = 1.0 - dsum / (double)(NB * NC);
  const double focal = acc->focal_num / ((double)acc->valid_pix + 1e-6);
  long long tt = 0, pp = 0;
  int nv = 0;
  double pensum = 0.0;
  for (int b = 0; b < NB; ++b) {
    tt += acc->tcount[b];
    pp += acc->pcount[b];
    if (acc->tcount[b] > 0) { nv++; pensum += (double)acc->pen[b]; }
  }
  double pen = 0.0;
  if (nv > 0) pen = pensum / fmax((double)nv * 2.0, 1.0);
  const double sep = (tt > 0 && pp > 0) ? 1.0 /*SEP_PW*/ * pen : 0.0;
  *out = (float)(ce + 0.5 * dice + 0.5 * focal + 0.3 * sep);
}

extern "C" void kernel_launch(void* const* d_in, const int* in_sizes, int n_in,
                              void* d_out, int out_size, void* d_ws, size_t ws_size,
                              hipStream_t stream) {
  (void)in_sizes; (void)n_in; (void)out_size;
  const float* pred = (const float*)d_in[0];
  const int* tgt = (const int*)d_in[1];
  const float* cw = (const float*)d_in[2];
  float* out = (float*)d_out;

  char* ws = (char*)d_ws;
  size_t off = (sizeof(Accum) + 1023) & ~(size_t)1023;
  Accum* acc = (Accum*)ws;
  unsigned long long* tmask = (unsigned long long*)(ws + off); off += NPIX / 8;
  unsigned long long* pmask = (unsigned long long*)(ws + off); off += NPIX / 8;

  // CC scratch: 6 int arrays of nbc*HW each; chunk batches to fit ws_size.
  const size_t per_batch = (size_t)6 * HW * sizeof(int);  // 6 MiB
  int nbc = 1;
  if (ws_size > off) {
    size_t fit = (ws_size - off) / per_batch;
    nbc = (int)(fit < 1 ? 1 : (fit > NB ? NB : fit));
  }
  int* tlab = (int*)(ws + off);
  int* plab = tlab + (size_t)nbc * HW;
  int* tmx  = plab + (size_t)nbc * HW;
  int* tmn  = tmx  + (size_t)nbc * HW;
  int* pmx  = tmn  + (size_t)nbc * HW;
  int* pmn  = pmx  + (size_t)nbc * HW;

  hipMemsetAsync(acc, 0, sizeof(Accum), stream);
  k_main<<<NB * 64, 256, 0, stream>>>(pred, tgt, cw, acc, tmask, pmask);
  for (int b0 = 0; b0 < NB; b0 += nbc) {
    const int nb = (NB - b0 < nbc) ? (NB - b0) : nbc;
    const int blocks = nb * (HW / 256);
    k_labinit<<<blocks, 256, 0, stream>>>(tmask, pmask, tlab, plab, tmx, tmn, pmx, pmn, acc, b0);
    k_merge<<<blocks, 256, 0, stream>>>(tlab, plab);
    k_flatten<<<blocks, 256, 0, stream>>>(tlab, plab);
    k_scatter<<<blocks, 256, 0, stream>>>(tlab, plab, tmx, tmn, pmx, pmn);
    k_count<<<blocks, 256, 0, stream>>>(tlab, plab, tmx, tmn, pmx, pmn, acc, b0);
  }
  k_final<<<1, 64, 0, stream>>>(acc, out);
}

// Round 2
// 649.087 us; speedup vs baseline: 2.7050x; 2.7050x over previous
//
#include <hip/hip_runtime.h>
#include <stdint.h>

// CombinedLoss: weighted CE + dice + focal + connected-component separation.
// B=16, C=3, H=W=512. Output: single f32 scalar.
//
// R2 pipeline (vs R1: k_labinit and k_flatten deleted, zero f64 atomics,
// wave-dedup'd scatter atomics):
//   memsets   : acc=0, tmx/pmx=0xFF (-1), tmn/pmn=0x7F (0x7f7f7f7f > any label)
//   k_main    : fused softmax losses -> per-block Partial (no atomics),
//               writes union-find seed labels tlab/plab directly
//   k_reduce  : 1 block, 16 waves (= images) sums 1024 Partials into Accum
//   k_merge   : one-pass union-find over 8-connectivity edges (atomicMin link)
//   k_scatter : per overlap pixel: on-the-fly root chase (plain loads; no
//               writers at this point) + wave-dedup by root -> leader atomics
//   k_count   : root with distinct-count>1 => penalty; block-reduced atomic
//   k_final   : combine into d_out[0]

#define NB 16
#define NC 3
#define HH 512
#define WW 512
#define HW (HH * WW)          // 262144
#define NPIX (NB * HW)        // 4194304
#define LOG2_HW 18
#define IGNORE_IDX 255
#define SCALE_IDX 2
#define BIGI 0x7f7f7f7f       // memset-able sentinel, > any label (< 2^18)

struct Accum {
  double ce_num, ce_den, focal_num;
  unsigned long long valid_pix;
  double sum_probs[NB * NC];
  double inter[NB * NC];
  unsigned long long cls_cnt[NB * NC];
  int tcount[NB];
  int pcount[NB];
  int pen[NB];
};

struct Partial {           // 96 B
  double d[9];             // ce_num, ce_den, focal, sp0..2, it0..2
  unsigned int u[6];       // c0, c1, c2, valid, tcnt, pcnt
};

__device__ __forceinline__ double wredd(double v) {
#pragma unroll
  for (int o = 32; o > 0; o >>= 1) v += __shfl_down(v, o, 64);
  return v;
}
__device__ __forceinline__ unsigned int wredu(unsigned int v) {
#pragma unroll
  for (int o = 32; o > 0; o >>= 1) v += __shfl_down(v, o, 64);
  return v;
}

// ---------- fused pointwise losses + label seeding ----------
__global__ __launch_bounds__(256) void k_main(
    const float* __restrict__ pred, const int* __restrict__ tgt,
    const float* __restrict__ cw, Partial* __restrict__ part,
    int* __restrict__ tlab, int* __restrict__ plab) {
  const int bid = blockIdx.x;
  const int b = bid >> 6;        // 64 blocks per batch image
  const int chunk = bid & 63;    // 4096 pixels per block, 16 iters of 256
  const int tid = threadIdx.x;
  const float w0 = cw[0], w1 = cw[1], w2 = cw[2];
  const float* __restrict__ pb = pred + (size_t)b * NC * HW;

  double ce_num = 0.0, ce_den = 0.0, focal = 0.0;
  double sp0 = 0, sp1 = 0, sp2 = 0, it0 = 0, it1 = 0, it2 = 0;
  unsigned int c0 = 0, c1 = 0, c2 = 0, vc = 0, tc_cnt = 0, pc_cnt = 0;

#pragma unroll 1
  for (int k = 0; k < 16; ++k) {
    const int i = (chunk << 12) + (k << 8) + tid;  // local pixel in image
    const int gp = (b << LOG2_HW) + i;
    const float x0 = pb[i];
    const float x1 = pb[i + HW];
    const float x2 = pb[i + 2 * HW];
    const int t = tgt[gp];

    // log_softmax, jax style: (x - max) - log(sum(exp(x - max)))
    const float m = fmaxf(fmaxf(x0, x1), x2);
    const float e0 = expf(x0 - m), e1 = expf(x1 - m), e2 = expf(x2 - m);
    const float s = e0 + e1 + e2;
    const float ls = logf(s);
    const float lp0 = (x0 - m) - ls, lp1 = (x1 - m) - ls, lp2 = (x2 - m) - ls;
    const float p0 = expf(lp0), p1 = expf(lp1), p2 = expf(lp2);  // ref: exp(logp)

    sp0 += (double)p0; sp1 += (double)p1; sp2 += (double)p2;

    const int tc = (t < 0) ? 0 : ((t > NC - 1) ? NC - 1 : t);
    const float lpt = (tc == 0) ? lp0 : ((tc == 1) ? lp1 : lp2);
    const float pt  = (tc == 0) ? p0  : ((tc == 1) ? p1  : p2);
    const float cwt = (tc == 0) ? w0  : ((tc == 1) ? w1  : w2);
    const float valid = (t != IGNORE_IDX) ? 1.0f : 0.0f;
    const float wv = cwt * valid;

    ce_num += (double)(wv * (-lpt));
    ce_den += (double)wv;
    const float om = 1.0f - pt;
    focal += (double)(cwt * om * om * (-lpt) * valid);
    vc += (t != IGNORE_IDX) ? 1u : 0u;

    if (t >= 0 && t < NC) {  // one_hot(out-of-range) == 0
      if (t == 0)      { it0 += (double)p0; c0++; }
      else if (t == 1) { it1 += (double)p1; c1++; }
      else             { it2 += (double)p2; c2++; }
    }

    // union-find seed labels for separation loss
    const bool tb = (t == SCALE_IDX);
    const float p2soft = e2 / s;            // jax.nn.softmax formula
    const bool pbit = (p2soft > 0.5f);
    tlab[gp] = tb ? i : -1;
    plab[gp] = pbit ? i : -1;
    tc_cnt += tb ? 1u : 0u;
    pc_cnt += pbit ? 1u : 0u;
  }

  // wave -> block reduction; thread0 stores one Partial (NO atomics)
  __shared__ double sd[4][9];
  __shared__ unsigned int si[4][6];
  const int wvid = tid >> 6, ln = tid & 63;
  const double r0 = wredd(ce_num), r1 = wredd(ce_den), r2 = wredd(focal),
               r3 = wredd(sp0), r4 = wredd(sp1), r5 = wredd(sp2),
               r6 = wredd(it0), r7 = wredd(it1), r8 = wredd(it2);
  const unsigned int u0 = wredu(c0), u1 = wredu(c1), u2 = wredu(c2),
                     u3 = wredu(vc), u4 = wredu(tc_cnt), u5 = wredu(pc_cnt);
  if (ln == 0) {
    sd[wvid][0] = r0; sd[wvid][1] = r1; sd[wvid][2] = r2;
    sd[wvid][3] = r3; sd[wvid][4] = r4; sd[wvid][5] = r5;
    sd[wvid][6] = r6; sd[wvid][7] = r7; sd[wvid][8] = r8;
    si[wvid][0] = u0; si[wvid][1] = u1; si[wvid][2] = u2;
    si[wvid][3] = u3; si[wvid][4] = u4; si[wvid][5] = u5;
  }
  __syncthreads();
  if (tid == 0) {
    Partial p;
    for (int q = 0; q < 9; ++q) p.d[q] = sd[0][q] + sd[1][q] + sd[2][q] + sd[3][q];
    for (int q = 0; q < 6; ++q) p.u[q] = si[0][q] + si[1][q] + si[2][q] + si[3][q];
    part[bid] = p;
  }
}

// ---------- single-block partial reduction (16 waves = 16 images) ----------
__global__ __launch_bounds__(1024) void k_reduce(
    const Partial* __restrict__ part, Accum* __restrict__ acc) {
  const int tid = threadIdx.x;
  const int w = tid >> 6, l = tid & 63;      // wave w owns image w, lane l = chunk l
  const Partial p = part[w * 64 + l];
  double d[9];
  unsigned int u[6];
#pragma unroll
  for (int q = 0; q < 9; ++q) d[q] = wredd(p.d[q]);
#pragma unroll
  for (int q = 0; q < 6; ++q) u[q] = wredu(p.u[q]);

  __shared__ double gsd[16][3];
  __shared__ unsigned int gsu[16];
  if (l == 0) {
    acc->sum_probs[w * NC + 0] = d[3];
    acc->sum_probs[w * NC + 1] = d[4];
    acc->sum_probs[w * NC + 2] = d[5];
    acc->inter[w * NC + 0] = d[6];
    acc->inter[w * NC + 1] = d[7];
    acc->inter[w * NC + 2] = d[8];
    acc->cls_cnt[w * NC + 0] = (unsigned long long)u[0];
    acc->cls_cnt[w * NC + 1] = (unsigned long long)u[1];
    acc->cls_cnt[w * NC + 2] = (unsigned long long)u[2];
    acc->tcount[w] = (int)u[4];
    acc->pcount[w] = (int)u[5];
    gsd[w][0] = d[0]; gsd[w][1] = d[1]; gsd[w][2] = d[2];
    gsu[w] = u[3];
  }
  __syncthreads();
  if (tid == 0) {
    double a0 = 0, a1 = 0, a2 = 0;
    unsigned long long av = 0;
    for (int q = 0; q < 16; ++q) {
      a0 += gsd[q][0]; a1 += gsd[q][1]; a2 += gsd[q][2]; av += gsu[q];
    }
    acc->ce_num = a0; acc->ce_den = a1; acc->focal_num = a2; acc->valid_pix = av;
  }
}

// ---------- union-find ----------
__device__ __forceinline__ int lread(int* p) {
  // bypass per-CU L1 during concurrent merge: peers' atomicMin land in L2
  return __hip_atomic_load(p, __ATOMIC_RELAXED, __HIP_MEMORY_SCOPE_AGENT);
}
__device__ __forceinline__ int findroot(int* L, int x) {
  int p = lread(&L[x]);
  while (p != x) { x = p; p = lread(&L[x]); }
  return x;
}
// read-only chase (no concurrent writers after k_merge; plain cached loads)
__device__ __forceinline__ int findroot_ro(const int* __restrict__ L, int x) {
  int p = L[x];
  while (p != x) { x = p; p = L[x]; }
  return x;
}
__device__ __forceinline__ void unite(int* L, int a, int b) {
  int la = findroot(L, a);
  int lb = findroot(L, b);
  while (la != lb) {
    if (la < lb) { int t = la; la = lb; lb = t; }  // la > lb
    const int old = atomicMin(&L[la], lb);
    if (old == la) break;  // linked a true root
    la = old;              // la was already linked; merge the old parent with lb
  }
}

__device__ __forceinline__ void merge_px(int* L, int i, int x) {
  if (L[i] < 0) return;  // sign never changes during merge; stale-safe
  if (x > 0 && L[i - 1] >= 0) unite(L, i, i - 1);
  if (i >= WW) {
    if (L[i - WW] >= 0) unite(L, i, i - WW);
    if (x > 0 && L[i - WW - 1] >= 0) unite(L, i, i - WW - 1);
    if (x < WW - 1 && L[i - WW + 1] >= 0) unite(L, i, i - WW + 1);
  }
}

__global__ __launch_bounds__(256) void k_merge(int* __restrict__ tlab, int* __restrict__ plab) {
  const int gt = blockIdx.x * 256 + threadIdx.x;
  const int bb = gt >> LOG2_HW;
  const int i = gt & (HW - 1);
  const int x = i & (WW - 1);
  merge_px(tlab + ((size_t)bb << LOG2_HW), i, x);
  merge_px(plab + ((size_t)bb << LOG2_HW), i, x);
}

// ---------- scatter: wave-dedup'd root-keyed min/max ----------
__device__ __forceinline__ void dedup_minmax(
    bool act, int key, int val, int* mx, int* mn, int lane) {
  // Partition wave by `key` among active lanes; one leader atomic pair per group.
  unsigned long long remaining = __ballot(act);
  while (remaining) {
    const int lead = (int)(__ffsll((long long)remaining) - 1);
    const int k = __shfl(key, lead, 64);
    const bool in = act && (key == k);
    const unsigned long long grp = __ballot(in);
    int vmx = in ? val : -1;
    int vmn = in ? val : BIGI;
#pragma unroll
    for (int o = 32; o > 0; o >>= 1) {
      vmx = max(vmx, __shfl_xor(vmx, o, 64));
      vmn = min(vmn, __shfl_xor(vmn, o, 64));
    }
    if (lane == lead) {
      atomicMax(&mx[k], vmx);
      atomicMin(&mn[k], vmn);
    }
    remaining &= ~grp;
  }
}

__global__ __launch_bounds__(256) void k_scatter(
    const int* __restrict__ tlab, const int* __restrict__ plab,
    int* __restrict__ tmx, int* __restrict__ tmn,
    int* __restrict__ pmx, int* __restrict__ pmn) {
  const int gt = blockIdx.x * 256 + threadIdx.x;
  const int bb = gt >> LOG2_HW;
  const int i = gt & (HW - 1);
  const size_t base = (size_t)bb << LOG2_HW;
  const int tl = tlab[gt];
  const int pl = plab[gt];
  const bool act = (tl >= 0) & (pl >= 0);
  int rt = 0, rp = 0;
  if (act) {
    rt = findroot_ro(tlab + base, i);
    rp = findroot_ro(plab + base, i);
  }
  const int lane = threadIdx.x & 63;
  dedup_minmax(act, rt, rp, tmx + base, tmn + base, lane);
  dedup_minmax(act, rp, rt, pmx + base, pmn + base, lane);
}

__global__ __launch_bounds__(256) void k_count(
    const int* __restrict__ tlab, const int* __restrict__ plab,
    const int* __restrict__ tmx, const int* __restrict__ tmn,
    const int* __restrict__ pmx, const int* __restrict__ pmn,
    Accum* __restrict__ acc) {
  const int gt = blockIdx.x * 256 + threadIdx.x;
  const int bb = gt >> LOG2_HW;
  const int i = gt & (HW - 1);
  int add = 0;
  if (tlab[gt] == i) {  // root <=> self-parent (min-linking only decreases)
    const int mx = tmx[gt];
    if (mx >= 0 && mx != tmn[gt]) add++;
  }
  if (plab[gt] == i) {
    const int mx = pmx[gt];
    if (mx >= 0 && mx != pmn[gt]) add++;
  }
  const int tid = threadIdx.x, ln = tid & 63, wv = tid >> 6;
#pragma unroll
  for (int o = 32; o > 0; o >>= 1) add += __shfl_down(add, o, 64);
  __shared__ int s4[4];
  if (ln == 0) s4[wv] = add;
  __syncthreads();
  if (tid == 0) {
    const int s = s4[0] + s4[1] + s4[2] + s4[3];
    if (s) atomicAdd(&acc->pen[bb], s);
  }
}

__global__ void k_final(const Accum* __restrict__ acc, float* __restrict__ out) {
  if (threadIdx.x != 0 || blockIdx.x != 0) return;
  const double ce = acc->ce_num / acc->ce_den;
  double dsum = 0.0;
  for (int k = 0; k < NB * NC; ++k) {
    const double un = acc->sum_probs[k] + (double)acc->cls_cnt[k];
    dsum += (2.0 * acc->inter[k] + 1e-6) / (un + 1e-6);
  }
  const double dice = 1.0 - dsum / (double)(NB * NC);
  const double focal = acc->focal_num / ((double)acc->valid_pix + 1e-6);
  long long tt = 0, pp = 0;
  int nv = 0;
  double pensum = 0.0;
  for (int b = 0; b < NB; ++b) {
    tt += acc->tcount[b];
    pp += acc->pcount[b];
    if (acc->tcount[b] > 0) { nv++; pensum += (double)acc->pen[b]; }
  }
  double pen = 0.0;
  if (nv > 0) pen = pensum / fmax((double)nv * 2.0, 1.0);
  const double sep = (tt > 0 && pp > 0) ? 1.0 /*SEP_PW*/ * pen : 0.0;
  *out = (float)(ce + 0.5 * dice + 0.5 * focal + 0.3 * sep);
}

extern "C" void kernel_launch(void* const* d_in, const int* in_sizes, int n_in,
                              void* d_out, int out_size, void* d_ws, size_t ws_size,
                              hipStream_t stream) {
  (void)in_sizes; (void)n_in; (void)out_size; (void)ws_size;
  const float* pred = (const float*)d_in[0];
  const int* tgt = (const int*)d_in[1];
  const float* cw = (const float*)d_in[2];
  float* out = (float*)d_out;

  char* ws = (char*)d_ws;
  Accum* acc = (Accum*)ws;
  size_t off = 2048;
  Partial* part = (Partial*)(ws + off); off += sizeof(Partial) * NB * 64;  // 98304
  int* tlab = (int*)(ws + off); off += (size_t)NPIX * 4;
  int* plab = (int*)(ws + off); off += (size_t)NPIX * 4;
  int* tmx  = (int*)(ws + off); off += (size_t)NPIX * 4;
  int* tmn  = (int*)(ws + off); off += (size_t)NPIX * 4;
  int* pmx  = (int*)(ws + off); off += (size_t)NPIX * 4;
  int* pmn  = (int*)(ws + off); off += (size_t)NPIX * 4;
  // total ~96.1 MiB; R1 profile proved ws_size >= ~97 MiB (nbc was 16)

  hipMemsetAsync(acc, 0, sizeof(Accum), stream);
  hipMemsetAsync(tmx, 0xFF, (size_t)NPIX * 4, stream);   // -1
  hipMemsetAsync(tmn, 0x7F, (size_t)NPIX * 4, stream);   // BIGI
  hipMemsetAsync(pmx, 0xFF, (size_t)NPIX * 4, stream);
  hipMemsetAsync(pmn, 0x7F, (size_t)NPIX * 4, stream);

  const int blocks = NPIX / 256;  // 16384
  k_main<<<NB * 64, 256, 0, stream>>>(pred, tgt, cw, part, tlab, plab);
  k_reduce<<<1, 1024, 0, stream>>>(part, acc);
  k_merge<<<blocks, 256, 0, stream>>>(tlab, plab);
  k_scatter<<<blocks, 256, 0, stream>>>(tlab, plab, tmx, tmn, pmx, pmn);
  k_count<<<blocks, 256, 0, stream>>>(tlab, plab, tmx, tmn, pmx, pmn, acc);
  k_final<<<1, 64, 0, stream>>>(acc, out);
}

// Round 3
// 487.930 us; speedup vs baseline: 3.5984x; 1.3303x over previous
//
#include <hip/hip_runtime.h>
#include <stdint.h>

// CombinedLoss: weighted CE + dice + focal + connected-component separation.
// B=16, C=3, H=W=512. Output: single f32 scalar.
//
// R3 pipeline (vs R2: global k_merge replaced by LDS-local CC + border-only
// global merge; {min,max} aux pairs replaced by single CAS conflict slot):
//   memsets   : acc=0, conf arrays=0
//   k_main    : fused softmax losses -> per-block Partial (no atomics),
//               bit-packed fg masks via ballot (1 MB total)
//   k_reduce  : 1 block sums 1024 Partials into Accum
//   k_local   : per 64x64 tile: full union-find in LDS, write depth-1
//               global labels (pixel -> global idx of tile-local root)
//   k_border  : global unite ONLY for tile-crossing edges (21 lines/img/mask)
//   k_scatter : overlap pixels: chase both roots (plain loads, no writers),
//               wave-dedup by root -> leader CAS into conflict slot
//   k_count   : root && conf==SENT => penalty; block-reduced atomic
//   k_final   : combine into d_out[0]

#define NB 16
#define NC 3
#define HH 512
#define WW 512
#define HW (HH * WW)          // 262144
#define NPIX (NB * HW)        // 4194304
#define LOG2_HW 18
#define IGNORE_IDX 255
#define SCALE_IDX 2
#define BIGI 0x7f7f7f7f
#define SENT (-1)             // conflict sentinel: >=2 distinct neighbor roots

struct Accum {
  double ce_num, ce_den, focal_num;
  unsigned long long valid_pix;
  double sum_probs[NB * NC];
  double inter[NB * NC];
  unsigned long long cls_cnt[NB * NC];
  int tcount[NB];
  int pcount[NB];
  int pen[NB];
};

struct Partial {           // 96 B
  double d[9];             // ce_num, ce_den, focal, sp0..2, it0..2
  unsigned int u[6];       // c0, c1, c2, valid, tcnt, pcnt
};

__device__ __forceinline__ double wredd(double v) {
#pragma unroll
  for (int o = 32; o > 0; o >>= 1) v += __shfl_down(v, o, 64);
  return v;
}
__device__ __forceinline__ unsigned int wredu(unsigned int v) {
#pragma unroll
  for (int o = 32; o > 0; o >>= 1) v += __shfl_down(v, o, 64);
  return v;
}

// ---------- fused pointwise losses + mask generation ----------
__global__ __launch_bounds__(256) void k_main(
    const float* __restrict__ pred, const int* __restrict__ tgt,
    const float* __restrict__ cw, Partial* __restrict__ part,
    unsigned long long* __restrict__ tmask, unsigned long long* __restrict__ pmask) {
  const int bid = blockIdx.x;
  const int b = bid >> 6;        // 64 blocks per batch image
  const int chunk = bid & 63;    // 4096 pixels per block, 16 iters of 256
  const int tid = threadIdx.x;
  const float w0 = cw[0], w1 = cw[1], w2 = cw[2];
  const float* __restrict__ pb = pred + (size_t)b * NC * HW;

  double ce_num = 0.0, ce_den = 0.0, focal = 0.0;
  double sp0 = 0, sp1 = 0, sp2 = 0, it0 = 0, it1 = 0, it2 = 0;
  unsigned int c0 = 0, c1 = 0, c2 = 0, vc = 0, tc_cnt = 0, pc_cnt = 0;

#pragma unroll 1
  for (int k = 0; k < 16; ++k) {
    const int i = (chunk << 12) + (k << 8) + tid;  // local pixel in image
    const int gp = (b << LOG2_HW) + i;
    const float x0 = pb[i];
    const float x1 = pb[i + HW];
    const float x2 = pb[i + 2 * HW];
    const int t = tgt[gp];

    // log_softmax, jax style: (x - max) - log(sum(exp(x - max)))
    const float m = fmaxf(fmaxf(x0, x1), x2);
    const float e0 = expf(x0 - m), e1 = expf(x1 - m), e2 = expf(x2 - m);
    const float s = e0 + e1 + e2;
    const float ls = logf(s);
    const float lp0 = (x0 - m) - ls, lp1 = (x1 - m) - ls, lp2 = (x2 - m) - ls;
    const float p0 = expf(lp0), p1 = expf(lp1), p2 = expf(lp2);  // ref: exp(logp)

    sp0 += (double)p0; sp1 += (double)p1; sp2 += (double)p2;

    const int tc = (t < 0) ? 0 : ((t > NC - 1) ? NC - 1 : t);
    const float lpt = (tc == 0) ? lp0 : ((tc == 1) ? lp1 : lp2);
    const float pt  = (tc == 0) ? p0  : ((tc == 1) ? p1  : p2);
    const float cwt = (tc == 0) ? w0  : ((tc == 1) ? w1  : w2);
    const float valid = (t != IGNORE_IDX) ? 1.0f : 0.0f;
    const float wv = cwt * valid;

    ce_num += (double)(wv * (-lpt));
    ce_den += (double)wv;
    const float om = 1.0f - pt;
    focal += (double)(cwt * om * om * (-lpt) * valid);
    vc += (t != IGNORE_IDX) ? 1u : 0u;

    if (t >= 0 && t < NC) {  // one_hot(out-of-range) == 0
      if (t == 0)      { it0 += (double)p0; c0++; }
      else if (t == 1) { it1 += (double)p1; c1++; }
      else             { it2 += (double)p2; c2++; }
    }

    // binary fg masks for separation loss (bit-packed via ballot)
    const bool tb = (t == SCALE_IDX);
    const float p2soft = e2 / s;            // jax.nn.softmax formula
    const bool pbit = (p2soft > 0.5f);
    const unsigned long long mt = __ballot(tb);
    const unsigned long long mp = __ballot(pbit);
    if ((tid & 63) == 0) {
      tmask[gp >> 6] = mt;
      pmask[gp >> 6] = mp;
    }
    tc_cnt += tb ? 1u : 0u;
    pc_cnt += pbit ? 1u : 0u;
  }

  // wave -> block reduction; thread0 stores one Partial (NO atomics)
  __shared__ double sd[4][9];
  __shared__ unsigned int si[4][6];
  const int wvid = tid >> 6, ln = tid & 63;
  const double r0 = wredd(ce_num), r1 = wredd(ce_den), r2 = wredd(focal),
               r3 = wredd(sp0), r4 = wredd(sp1), r5 = wredd(sp2),
               r6 = wredd(it0), r7 = wredd(it1), r8 = wredd(it2);
  const unsigned int u0 = wredu(c0), u1 = wredu(c1), u2 = wredu(c2),
                     u3 = wredu(vc), u4 = wredu(tc_cnt), u5 = wredu(pc_cnt);
  if (ln == 0) {
    sd[wvid][0] = r0; sd[wvid][1] = r1; sd[wvid][2] = r2;
    sd[wvid][3] = r3; sd[wvid][4] = r4; sd[wvid][5] = r5;
    sd[wvid][6] = r6; sd[wvid][7] = r7; sd[wvid][8] = r8;
    si[wvid][0] = u0; si[wvid][1] = u1; si[wvid][2] = u2;
    si[wvid][3] = u3; si[wvid][4] = u4; si[wvid][5] = u5;
  }
  __syncthreads();
  if (tid == 0) {
    Partial p;
    for (int q = 0; q < 9; ++q) p.d[q] = sd[0][q] + sd[1][q] + sd[2][q] + sd[3][q];
    for (int q = 0; q < 6; ++q) p.u[q] = si[0][q] + si[1][q] + si[2][q] + si[3][q];
    part[bid] = p;
  }
}

// ---------- single-block partial reduction (16 waves = 16 images) ----------
__global__ __launch_bounds__(1024) void k_reduce(
    const Partial* __restrict__ part, Accum* __restrict__ acc) {
  const int tid = threadIdx.x;
  const int w = tid >> 6, l = tid & 63;      // wave w owns image w, lane l = chunk l
  const Partial p = part[w * 64 + l];
  double d[9];
  unsigned int u[6];
#pragma unroll
  for (int q = 0; q < 9; ++q) d[q] = wredd(p.d[q]);
#pragma unroll
  for (int q = 0; q < 6; ++q) u[q] = wredu(p.u[q]);

  __shared__ double gsd[16][3];
  __shared__ unsigned int gsu[16];
  if (l == 0) {
    acc->sum_probs[w * NC + 0] = d[3];
    acc->sum_probs[w * NC + 1] = d[4];
    acc->sum_probs[w * NC + 2] = d[5];
    acc->inter[w * NC + 0] = d[6];
    acc->inter[w * NC + 1] = d[7];
    acc->inter[w * NC + 2] = d[8];
    acc->cls_cnt[w * NC + 0] = (unsigned long long)u[0];
    acc->cls_cnt[w * NC + 1] = (unsigned long long)u[1];
    acc->cls_cnt[w * NC + 2] = (unsigned long long)u[2];
    acc->tcount[w] = (int)u[4];
    acc->pcount[w] = (int)u[5];
    gsd[w][0] = d[0]; gsd[w][1] = d[1]; gsd[w][2] = d[2];
    gsu[w] = u[3];
  }
  __syncthreads();
  if (tid == 0) {
    double a0 = 0, a1 = 0, a2 = 0;
    unsigned long long av = 0;
    for (int q = 0; q < 16; ++q) {
      a0 += gsd[q][0]; a1 += gsd[q][1]; a2 += gsd[q][2]; av += gsu[q];
    }
    acc->ce_num = a0; acc->ce_den = a1; acc->focal_num = a2; acc->valid_pix = av;
  }
}

// ---------- LDS union-find (tile-local) ----------
__device__ __forceinline__ int find_lds(volatile int* par, int x) {
  int p = par[x];
  while (p != x) { x = p; p = par[x]; }
  return x;
}
__device__ __forceinline__ void unite_lds(int* par, int a, int b) {
  int la = find_lds(par, a);
  int lb = find_lds(par, b);
  while (la != lb) {
    if (la < lb) { int t = la; la = lb; lb = t; }  // la > lb
    const int old = atomicMin(&par[la], lb);
    if (old == la) break;
    la = old;
  }
}

// one block = one (image, mask, 64x64 tile); full CC in LDS
__global__ __launch_bounds__(256) void k_local(
    const unsigned long long* __restrict__ tmask,
    const unsigned long long* __restrict__ pmask,
    int* __restrict__ tlab, int* __restrict__ plab) {
  const int idx = blockIdx.x;
  const int img = idx >> 7;
  const int rest = idx & 127;
  const int maskid = rest >> 6;
  const int tile = rest & 63;
  const int ty = tile >> 3, tx = tile & 7;
  const unsigned long long* __restrict__ mg =
      (maskid ? pmask : tmask) + (size_t)img * (HW / 64);
  int* __restrict__ lab = (maskid ? plab : tlab) + ((size_t)img << LOG2_HW);
  const int tid = threadIdx.x;

  __shared__ int par[4096];
  __shared__ unsigned long long mw[64];
  if (tid < 64) mw[tid] = mg[(ty * 64 + tid) * 8 + tx];  // tile row = 1 u64 word
  __syncthreads();
#pragma unroll
  for (int k = 0; k < 16; ++k) {
    const int li = (k << 8) + tid;
    par[li] = ((mw[li >> 6] >> (li & 63)) & 1ull) ? li : -1;
  }
  __syncthreads();
#pragma unroll 1
  for (int k = 0; k < 16; ++k) {
    const int li = (k << 8) + tid;
    if (par[li] < 0) continue;  // sign stable during merge
    const int x = li & 63, y = li >> 6;
    if (x > 0 && par[li - 1] >= 0) unite_lds(par, li, li - 1);
    if (y > 0) {
      if (par[li - 64] >= 0) unite_lds(par, li, li - 64);
      if (x > 0 && par[li - 65] >= 0) unite_lds(par, li, li - 65);
      if (x < 63 && par[li - 63] >= 0) unite_lds(par, li, li - 63);
    }
  }
  __syncthreads();
#pragma unroll 1
  for (int k = 0; k < 16; ++k) {
    const int li = (k << 8) + tid;
    const int y = li >> 6, x = li & 63;
    int out = -1;
    if (par[li] >= 0) {
      int r = li, p = par[li];
      while (p != r) { r = p; p = par[r]; }  // static after barrier
      out = (ty * 64 + (r >> 6)) * WW + tx * 64 + (r & 63);  // global idx of root
    }
    lab[(ty * 64 + y) * WW + tx * 64 + x] = out;
  }
}

// ---------- global union-find (border edges only) ----------
__device__ __forceinline__ int lread(int* p) {
  return __hip_atomic_load(p, __ATOMIC_RELAXED, __HIP_MEMORY_SCOPE_AGENT);
}
__device__ __forceinline__ int findroot(int* L, int x) {
  int p = lread(&L[x]);
  while (p != x) { x = p; p = lread(&L[x]); }
  return x;
}
__device__ __forceinline__ int findroot_ro(const int* __restrict__ L, int x) {
  int p = L[x];
  while (p != x) { x = p; p = L[x]; }
  return x;
}
__device__ __forceinline__ void unite(int* L, int a, int b) {
  int la = findroot(L, a);
  int lb = findroot(L, b);
  while (la != lb) {
    if (la < lb) { int t = la; la = lb; lb = t; }
    const int old = atomicMin(&L[la], lb);
    if (old == la) break;
    la = old;
  }
}

// 21 lines per (img, mask): 7 horiz rows y=64k; 7 vert cols x=64k; 7 cols x=64k-1
__global__ __launch_bounds__(256) void k_border(int* __restrict__ tlab, int* __restrict__ plab) {
  const int t = blockIdx.x * 256 + threadIdx.x;  // 344064 total
  const int pos = t & 511;
  const int rest = t >> 9;          // 0..671
  const int line = rest % 21;
  const int rest2 = rest / 21;      // 0..31
  const int maskid = rest2 & 1;
  const int img = rest2 >> 1;
  int* __restrict__ lab = (maskid ? plab : tlab) + ((size_t)img << LOG2_HW);
  if (line < 7) {                        // horizontal border row
    const int i = (((line + 1) << 6) * WW) + pos;
    if (lab[i] < 0) return;
    if (lab[i - WW] >= 0) unite(lab, i, i - WW);                      // N
    if (pos > 0 && lab[i - WW - 1] >= 0) unite(lab, i, i - WW - 1);   // NW
    if (pos < WW - 1 && lab[i - WW + 1] >= 0) unite(lab, i, i - WW + 1);  // NE
  } else if (line < 14) {                // vertical border, left col x=64k
    const int i = pos * WW + ((line - 6) << 6);
    if (lab[i] < 0) return;
    if (lab[i - 1] >= 0) unite(lab, i, i - 1);                        // W
    if (pos > 0 && lab[i - WW - 1] >= 0) unite(lab, i, i - WW - 1);   // NW
  } else {                               // vertical border, right col x=64k-1
    if (pos == 0) return;
    const int i = pos * WW + (((line - 13) << 6) - 1);
    if (lab[i] < 0) return;
    if (lab[i - WW + 1] >= 0) unite(lab, i, i - WW + 1);              // NE
  }
}

// ---------- scatter: wave-dedup'd conflict detection ----------
// conf slot: 0 = empty, v+1 = single distinct neighbor root v, SENT = >=2 distinct
__device__ __forceinline__ void dedup_conf(
    bool act, int key, int val, int* __restrict__ conf, int lane) {
  unsigned long long remaining = __ballot(act);
  while (remaining) {
    const int lead = (int)(__ffsll((long long)remaining) - 1);
    const int k = __shfl(key, lead, 64);
    const bool in = act && (key == k);
    const unsigned long long grp = __ballot(in);
    int vmx = in ? val : -1;
    int vmn = in ? val : BIGI;
#pragma unroll
    for (int o = 32; o > 0; o >>= 1) {
      vmx = max(vmx, __shfl_xor(vmx, o, 64));
      vmn = min(vmn, __shfl_xor(vmn, o, 64));
    }
    if (lane == lead) {
      int* slot = &conf[k];
      const int cur = __hip_atomic_load(slot, __ATOMIC_RELAXED, __HIP_MEMORY_SCOPE_AGENT);
      if (cur != SENT) {
        if (vmx != vmn) {
          atomicExch(slot, SENT);
        } else {
          const int old = atomicCAS(slot, 0, vmx + 1);
          if (old != 0 && old != vmx + 1) atomicExch(slot, SENT);
        }
      }
    }
    remaining &= ~grp;
  }
}

__global__ __launch_bounds__(256) void k_scatter(
    const int* __restrict__ tlab, const int* __restrict__ plab,
    int* __restrict__ tconf, int* __restrict__ pconf) {
  const int gt = blockIdx.x * 256 + threadIdx.x;
  const int bb = gt >> LOG2_HW;
  const int i = gt & (HW - 1);
  const size_t base = (size_t)bb << LOG2_HW;
  const int tl = tlab[gt];
  const int pl = plab[gt];
  const bool act = (tl >= 0) & (pl >= 0);
  int rt = 0, rp = 0;
  if (act) {
    rt = findroot_ro(tlab + base, i);  // no writers at this point
    rp = findroot_ro(plab + base, i);
  }
  const int lane = threadIdx.x & 63;
  dedup_conf(act, rt, rp, tconf + base, lane);
  dedup_conf(act, rp, rt, pconf + base, lane);
}

__global__ __launch_bounds__(256) void k_count(
    const int* __restrict__ tlab, const int* __restrict__ plab,
    const int* __restrict__ tconf, const int* __restrict__ pconf,
    Accum* __restrict__ acc) {
  const int gt = blockIdx.x * 256 + threadIdx.x;
  const int bb = gt >> LOG2_HW;
  const int i = gt & (HW - 1);
  int add = 0;
  if (tlab[gt] == i && tconf[gt] == SENT) add++;  // root with >=2 distinct preds
  if (plab[gt] == i && pconf[gt] == SENT) add++;
  const int tid = threadIdx.x, ln = tid & 63, wv = tid >> 6;
#pragma unroll
  for (int o = 32; o > 0; o >>= 1) add += __shfl_down(add, o, 64);
  __shared__ int s4[4];
  if (ln == 0) s4[wv] = add;
  __syncthreads();
  if (tid == 0) {
    const int s = s4[0] + s4[1] + s4[2] + s4[3];
    if (s) atomicAdd(&acc->pen[bb], s);
  }
}

__global__ void k_final(const Accum* __restrict__ acc, float* __restrict__ out) {
  if (threadIdx.x != 0 || blockIdx.x != 0) return;
  const double ce = acc->ce_num / acc->ce_den;
  double dsum = 0.0;
  for (int k = 0; k < NB * NC; ++k) {
    const double un = acc->sum_probs[k] + (double)acc->cls_cnt[k];
    dsum += (2.0 * acc->inter[k] + 1e-6) / (un + 1e-6);
  }
  const double dice = 1.0 - dsum / (double)(NB * NC);
  const double focal = acc->focal_num / ((double)acc->valid_pix + 1e-6);
  long long tt = 0, pp = 0;
  int nv = 0;
  double pensum = 0.0;
  for (int b = 0; b < NB; ++b) {
    tt += acc->tcount[b];
    pp += acc->pcount[b];
    if (acc->tcount[b] > 0) { nv++; pensum += (double)acc->pen[b]; }
  }
  double pen = 0.0;
  if (nv > 0) pen = pensum / fmax((double)nv * 2.0, 1.0);
  const double sep = (tt > 0 && pp > 0) ? 1.0 /*SEP_PW*/ * pen : 0.0;
  *out = (float)(ce + 0.5 * dice + 0.5 * focal + 0.3 * sep);
}

extern "C" void kernel_launch(void* const* d_in, const int* in_sizes, int n_in,
                              void* d_out, int out_size, void* d_ws, size_t ws_size,
                              hipStream_t stream) {
  (void)in_sizes; (void)n_in; (void)out_size; (void)ws_size;
  const float* pred = (const float*)d_in[0];
  const int* tgt = (const int*)d_in[1];
  const float* cw = (const float*)d_in[2];
  float* out = (float*)d_out;

  char* ws = (char*)d_ws;
  Accum* acc = (Accum*)ws;
  size_t off = 2048;
  Partial* part = (Partial*)(ws + off); off += sizeof(Partial) * NB * 64;  // 98304
  unsigned long long* tmask = (unsigned long long*)(ws + off); off += NPIX / 8;
  unsigned long long* pmask = (unsigned long long*)(ws + off); off += NPIX / 8;
  int* tlab  = (int*)(ws + off); off += (size_t)NPIX * 4;
  int* plab  = (int*)(ws + off); off += (size_t)NPIX * 4;
  int* tconf = (int*)(ws + off); off += (size_t)NPIX * 4;
  int* pconf = (int*)(ws + off); off += (size_t)NPIX * 4;
  // total ~68.3 MiB (R1 proved ws_size >= ~97 MiB)

  hipMemsetAsync(acc, 0, sizeof(Accum), stream);
  hipMemsetAsync(tconf, 0, (size_t)NPIX * 8, stream);  // tconf+pconf contiguous

  const int blocks = NPIX / 256;  // 16384
  k_main<<<NB * 64, 256, 0, stream>>>(pred, tgt, cw, part, tmask, pmask);
  k_reduce<<<1, 1024, 0, stream>>>(part, acc);
  k_local<<<NB * 64 * 2, 256, 0, stream>>>(tmask, pmask, tlab, plab);
  k_border<<<(NB * 2 * 21 * 512) / 256, 256, 0, stream>>>(tlab, plab);
  k_scatter<<<blocks, 256, 0, stream>>>(tlab, plab, tconf, pconf);
  k_count<<<blocks, 256, 0, stream>>>(tlab, plab, tconf, pconf, acc);
  k_final<<<1, 64, 0, stream>>>(acc, out);
}

// Round 4
// 303.377 us; speedup vs baseline: 5.7874x; 1.6083x over previous
//
#include <hip/hip_runtime.h>
#include <stdint.h>

// CombinedLoss: weighted CE + dice + focal + connected-component separation.
// B=16, C=3, H=W=512. Output: single f32 scalar.
//
// R4 pipeline (vs R3: k_count atomic chain removed -> penpart array + fused
// final reduce; k_scatter drops wave-dedup, uses mask-based activity + direct
// monotone CAS protocol):
//   memsets   : acc=0, conf arrays=0
//   k_main    : fused softmax losses -> per-block Partial (no atomics),
//               bit-packed fg masks via ballot (1 MB total)
//   k_reduce  : 1 block sums 1024 Partials into Accum
//   k_local   : per 64x64 tile: full union-find in LDS, write depth-1
//               global labels (pixel -> global idx of tile-local root)
//   k_border  : global unite ONLY for tile-crossing edges
//   k_scatter : active px from masks; chase both roots (plain loads);
//               conf slot monotone update: 0 -> val+1 -> SENT
//   k_count   : root && conf==SENT => block sum -> penpart[bid] (NO atomics)
//   k_final   : 16 waves reduce penpart per image + combine into d_out[0]

#define NB 16
#define NC 3
#define HH 512
#define WW 512
#define HW (HH * WW)          // 262144
#define NPIX (NB * HW)        // 4194304
#define LOG2_HW 18
#define IGNORE_IDX 255
#define SCALE_IDX 2
#define SENT (-1)             // conflict sentinel: >=2 distinct neighbor roots

struct Accum {
  double ce_num, ce_den, focal_num;
  unsigned long long valid_pix;
  double sum_probs[NB * NC];
  double inter[NB * NC];
  unsigned long long cls_cnt[NB * NC];
  int tcount[NB];
  int pcount[NB];
  int pen[NB];
};

struct Partial {           // 96 B
  double d[9];             // ce_num, ce_den, focal, sp0..2, it0..2
  unsigned int u[6];       // c0, c1, c2, valid, tcnt, pcnt
};

__device__ __forceinline__ double wredd(double v) {
#pragma unroll
  for (int o = 32; o > 0; o >>= 1) v += __shfl_down(v, o, 64);
  return v;
}
__device__ __forceinline__ unsigned int wredu(unsigned int v) {
#pragma unroll
  for (int o = 32; o > 0; o >>= 1) v += __shfl_down(v, o, 64);
  return v;
}

// ---------- fused pointwise losses + mask generation ----------
__global__ __launch_bounds__(256) void k_main(
    const float* __restrict__ pred, const int* __restrict__ tgt,
    const float* __restrict__ cw, Partial* __restrict__ part,
    unsigned long long* __restrict__ tmask, unsigned long long* __restrict__ pmask) {
  const int bid = blockIdx.x;
  const int b = bid >> 6;        // 64 blocks per batch image
  const int chunk = bid & 63;    // 4096 pixels per block, 16 iters of 256
  const int tid = threadIdx.x;
  const float w0 = cw[0], w1 = cw[1], w2 = cw[2];
  const float* __restrict__ pb = pred + (size_t)b * NC * HW;

  double ce_num = 0.0, ce_den = 0.0, focal = 0.0;
  double sp0 = 0, sp1 = 0, sp2 = 0, it0 = 0, it1 = 0, it2 = 0;
  unsigned int c0 = 0, c1 = 0, c2 = 0, vc = 0, tc_cnt = 0, pc_cnt = 0;

#pragma unroll 1
  for (int k = 0; k < 16; ++k) {
    const int i = (chunk << 12) + (k << 8) + tid;  // local pixel in image
    const int gp = (b << LOG2_HW) + i;
    const float x0 = pb[i];
    const float x1 = pb[i + HW];
    const float x2 = pb[i + 2 * HW];
    const int t = tgt[gp];

    // log_softmax, jax style: (x - max) - log(sum(exp(x - max)))
    const float m = fmaxf(fmaxf(x0, x1), x2);
    const float e0 = expf(x0 - m), e1 = expf(x1 - m), e2 = expf(x2 - m);
    const float s = e0 + e1 + e2;
    const float ls = logf(s);
    const float lp0 = (x0 - m) - ls, lp1 = (x1 - m) - ls, lp2 = (x2 - m) - ls;
    const float p0 = expf(lp0), p1 = expf(lp1), p2 = expf(lp2);  // ref: exp(logp)

    sp0 += (double)p0; sp1 += (double)p1; sp2 += (double)p2;

    const int tc = (t < 0) ? 0 : ((t > NC - 1) ? NC - 1 : t);
    const float lpt = (tc == 0) ? lp0 : ((tc == 1) ? lp1 : lp2);
    const float pt  = (tc == 0) ? p0  : ((tc == 1) ? p1  : p2);
    const float cwt = (tc == 0) ? w0  : ((tc == 1) ? w1  : w2);
    const float valid = (t != IGNORE_IDX) ? 1.0f : 0.0f;
    const float wv = cwt * valid;

    ce_num += (double)(wv * (-lpt));
    ce_den += (double)wv;
    const float om = 1.0f - pt;
    focal += (double)(cwt * om * om * (-lpt) * valid);
    vc += (t != IGNORE_IDX) ? 1u : 0u;

    if (t >= 0 && t < NC) {  // one_hot(out-of-range) == 0
      if (t == 0)      { it0 += (double)p0; c0++; }
      else if (t == 1) { it1 += (double)p1; c1++; }
      else             { it2 += (double)p2; c2++; }
    }

    // binary fg masks for separation loss (bit-packed via ballot)
    const bool tb = (t == SCALE_IDX);
    const float p2soft = e2 / s;            // jax.nn.softmax formula
    const bool pbit = (p2soft > 0.5f);
    const unsigned long long mt = __ballot(tb);
    const unsigned long long mp = __ballot(pbit);
    if ((tid & 63) == 0) {
      tmask[gp >> 6] = mt;
      pmask[gp >> 6] = mp;
    }
    tc_cnt += tb ? 1u : 0u;
    pc_cnt += pbit ? 1u : 0u;
  }

  // wave -> block reduction; thread0 stores one Partial (NO atomics)
  __shared__ double sd[4][9];
  __shared__ unsigned int si[4][6];
  const int wvid = tid >> 6, ln = tid & 63;
  const double r0 = wredd(ce_num), r1 = wredd(ce_den), r2 = wredd(focal),
               r3 = wredd(sp0), r4 = wredd(sp1), r5 = wredd(sp2),
               r6 = wredd(it0), r7 = wredd(it1), r8 = wredd(it2);
  const unsigned int u0 = wredu(c0), u1 = wredu(c1), u2 = wredu(c2),
                     u3 = wredu(vc), u4 = wredu(tc_cnt), u5 = wredu(pc_cnt);
  if (ln == 0) {
    sd[wvid][0] = r0; sd[wvid][1] = r1; sd[wvid][2] = r2;
    sd[wvid][3] = r3; sd[wvid][4] = r4; sd[wvid][5] = r5;
    sd[wvid][6] = r6; sd[wvid][7] = r7; sd[wvid][8] = r8;
    si[wvid][0] = u0; si[wvid][1] = u1; si[wvid][2] = u2;
    si[wvid][3] = u3; si[wvid][4] = u4; si[wvid][5] = u5;
  }
  __syncthreads();
  if (tid == 0) {
    Partial p;
    for (int q = 0; q < 9; ++q) p.d[q] = sd[0][q] + sd[1][q] + sd[2][q] + sd[3][q];
    for (int q = 0; q < 6; ++q) p.u[q] = si[0][q] + si[1][q] + si[2][q] + si[3][q];
    part[bid] = p;
  }
}

// ---------- single-block partial reduction (16 waves = 16 images) ----------
__global__ __launch_bounds__(1024) void k_reduce(
    const Partial* __restrict__ part, Accum* __restrict__ acc) {
  const int tid = threadIdx.x;
  const int w = tid >> 6, l = tid & 63;      // wave w owns image w, lane l = chunk l
  const Partial p = part[w * 64 + l];
  double d[9];
  unsigned int u[6];
#pragma unroll
  for (int q = 0; q < 9; ++q) d[q] = wredd(p.d[q]);
#pragma unroll
  for (int q = 0; q < 6; ++q) u[q] = wredu(p.u[q]);

  __shared__ double gsd[16][3];
  __shared__ unsigned int gsu[16];
  if (l == 0) {
    acc->sum_probs[w * NC + 0] = d[3];
    acc->sum_probs[w * NC + 1] = d[4];
    acc->sum_probs[w * NC + 2] = d[5];
    acc->inter[w * NC + 0] = d[6];
    acc->inter[w * NC + 1] = d[7];
    acc->inter[w * NC + 2] = d[8];
    acc->cls_cnt[w * NC + 0] = (unsigned long long)u[0];
    acc->cls_cnt[w * NC + 1] = (unsigned long long)u[1];
    acc->cls_cnt[w * NC + 2] = (unsigned long long)u[2];
    acc->tcount[w] = (int)u[4];
    acc->pcount[w] = (int)u[5];
    gsd[w][0] = d[0]; gsd[w][1] = d[1]; gsd[w][2] = d[2];
    gsu[w] = u[3];
  }
  __syncthreads();
  if (tid == 0) {
    double a0 = 0, a1 = 0, a2 = 0;
    unsigned long long av = 0;
    for (int q = 0; q < 16; ++q) {
      a0 += gsd[q][0]; a1 += gsd[q][1]; a2 += gsd[q][2]; av += gsu[q];
    }
    acc->ce_num = a0; acc->ce_den = a1; acc->focal_num = a2; acc->valid_pix = av;
  }
}

// ---------- LDS union-find (tile-local) ----------
__device__ __forceinline__ int find_lds(volatile int* par, int x) {
  int p = par[x];
  while (p != x) { x = p; p = par[x]; }
  return x;
}
__device__ __forceinline__ void unite_lds(int* par, int a, int b) {
  int la = find_lds(par, a);
  int lb = find_lds(par, b);
  while (la != lb) {
    if (la < lb) { int t = la; la = lb; lb = t; }  // la > lb
    const int old = atomicMin(&par[la], lb);
    if (old == la) break;
    la = old;
  }
}

// one block = one (image, mask, 64x64 tile); full CC in LDS
__global__ __launch_bounds__(256) void k_local(
    const unsigned long long* __restrict__ tmask,
    const unsigned long long* __restrict__ pmask,
    int* __restrict__ tlab, int* __restrict__ plab) {
  const int idx = blockIdx.x;
  const int img = idx >> 7;
  const int rest = idx & 127;
  const int maskid = rest >> 6;
  const int tile = rest & 63;
  const int ty = tile >> 3, tx = tile & 7;
  const unsigned long long* __restrict__ mg =
      (maskid ? pmask : tmask) + (size_t)img * (HW / 64);
  int* __restrict__ lab = (maskid ? plab : tlab) + ((size_t)img << LOG2_HW);
  const int tid = threadIdx.x;

  __shared__ int par[4096];
  __shared__ unsigned long long mw[64];
  if (tid < 64) mw[tid] = mg[(ty * 64 + tid) * 8 + tx];  // tile row = 1 u64 word
  __syncthreads();
#pragma unroll
  for (int k = 0; k < 16; ++k) {
    const int li = (k << 8) + tid;
    par[li] = ((mw[li >> 6] >> (li & 63)) & 1ull) ? li : -1;
  }
  __syncthreads();
#pragma unroll 1
  for (int k = 0; k < 16; ++k) {
    const int li = (k << 8) + tid;
    if (par[li] < 0) continue;  // sign stable during merge
    const int x = li & 63, y = li >> 6;
    if (x > 0 && par[li - 1] >= 0) unite_lds(par, li, li - 1);
    if (y > 0) {
      if (par[li - 64] >= 0) unite_lds(par, li, li - 64);
      if (x > 0 && par[li - 65] >= 0) unite_lds(par, li, li - 65);
      if (x < 63 && par[li - 63] >= 0) unite_lds(par, li, li - 63);
    }
  }
  __syncthreads();
#pragma unroll 1
  for (int k = 0; k < 16; ++k) {
    const int li = (k << 8) + tid;
    const int y = li >> 6, x = li & 63;
    int out = -1;
    if (par[li] >= 0) {
      int r = li, p = par[li];
      while (p != r) { r = p; p = par[r]; }  // static after barrier
      out = (ty * 64 + (r >> 6)) * WW + tx * 64 + (r & 63);  // global idx of root
    }
    lab[(ty * 64 + y) * WW + tx * 64 + x] = out;
  }
}

// ---------- global union-find (border edges only) ----------
__device__ __forceinline__ int lread(int* p) {
  return __hip_atomic_load(p, __ATOMIC_RELAXED, __HIP_MEMORY_SCOPE_AGENT);
}
__device__ __forceinline__ int findroot(int* L, int x) {
  int p = lread(&L[x]);
  while (p != x) { x = p; p = lread(&L[x]); }
  return x;
}
__device__ __forceinline__ int findroot_ro(const int* __restrict__ L, int x) {
  int p = L[x];
  while (p != x) { x = p; p = L[x]; }
  return x;
}
__device__ __forceinline__ void unite(int* L, int a, int b) {
  int la = findroot(L, a);
  int lb = findroot(L, b);
  while (la != lb) {
    if (la < lb) { int t = la; la = lb; lb = t; }
    const int old = atomicMin(&L[la], lb);
    if (old == la) break;
    la = old;
  }
}

// 21 lines per (img, mask): 7 horiz rows y=64k; 7 vert cols x=64k; 7 cols x=64k-1
__global__ __launch_bounds__(256) void k_border(int* __restrict__ tlab, int* __restrict__ plab) {
  const int t = blockIdx.x * 256 + threadIdx.x;  // 344064 total
  const int pos = t & 511;
  const int rest = t >> 9;          // 0..671
  const int line = rest % 21;
  const int rest2 = rest / 21;      // 0..31
  const int maskid = rest2 & 1;
  const int img = rest2 >> 1;
  int* __restrict__ lab = (maskid ? plab : tlab) + ((size_t)img << LOG2_HW);
  if (line < 7) {                        // horizontal border row
    const int i = (((line + 1) << 6) * WW) + pos;
    if (lab[i] < 0) return;
    if (lab[i - WW] >= 0) unite(lab, i, i - WW);                      // N
    if (pos > 0 && lab[i - WW - 1] >= 0) unite(lab, i, i - WW - 1);   // NW
    if (pos < WW - 1 && lab[i - WW + 1] >= 0) unite(lab, i, i - WW + 1);  // NE
  } else if (line < 14) {                // vertical border, left col x=64k
    const int i = pos * WW + ((line - 6) << 6);
    if (lab[i] < 0) return;
    if (lab[i - 1] >= 0) unite(lab, i, i - 1);                        // W
    if (pos > 0 && lab[i - WW - 1] >= 0) unite(lab, i, i - WW - 1);   // NW
  } else {                               // vertical border, right col x=64k-1
    if (pos == 0) return;
    const int i = pos * WW + (((line - 13) << 6) - 1);
    if (lab[i] < 0) return;
    if (lab[i - WW + 1] >= 0) unite(lab, i, i - WW + 1);              // NE
  }
}

// ---------- scatter: monotone conflict slot 0 -> val+1 -> SENT ----------
__device__ __forceinline__ void conf_update(int* __restrict__ conf, int key, int val) {
  int* slot = &conf[key];
  const int tag = val + 1;  // val < 2^18, so tag > 0 and != SENT
  const int cur = __hip_atomic_load(slot, __ATOMIC_RELAXED, __HIP_MEMORY_SCOPE_AGENT);
  if (cur == SENT || cur == tag) return;  // monotone: SENT is final, tag adds nothing
  if (cur == 0) {
    const int old = atomicCAS(slot, 0, tag);
    if (old == 0 || old == tag || old == SENT) return;
    atomicExch(slot, SENT);  // raced with a different tag
    return;
  }
  atomicExch(slot, SENT);    // saw a different tag
}

__global__ __launch_bounds__(256) void k_scatter(
    const unsigned long long* __restrict__ tmask,
    const unsigned long long* __restrict__ pmask,
    const int* __restrict__ tlab, const int* __restrict__ plab,
    int* __restrict__ tconf, int* __restrict__ pconf) {
  const int gt = blockIdx.x * 256 + threadIdx.x;
  const int bb = gt >> LOG2_HW;
  const int i = gt & (HW - 1);
  const size_t base = (size_t)bb << LOG2_HW;
  const int lane = threadIdx.x & 63;
  // whole wave shares one mask word (broadcast load)
  const unsigned long long tw = tmask[gt >> 6];
  const unsigned long long pw = pmask[gt >> 6];
  const bool act = ((tw >> lane) & 1ull) & ((pw >> lane) & 1ull);
  if (!act) return;
  const int rt = findroot_ro(tlab + base, i);  // no writers at this point
  const int rp = findroot_ro(plab + base, i);
  conf_update(tconf + base, rt, rp);
  conf_update(pconf + base, rp, rt);
}

__global__ __launch_bounds__(256) void k_count(
    const int* __restrict__ tlab, const int* __restrict__ plab,
    const int* __restrict__ tconf, const int* __restrict__ pconf,
    int* __restrict__ penpart) {
  const int gt = blockIdx.x * 256 + threadIdx.x;
  const int i = gt & (HW - 1);
  int add = 0;
  if (tlab[gt] == i && tconf[gt] == SENT) add++;  // root with >=2 distinct preds
  if (plab[gt] == i && pconf[gt] == SENT) add++;
  const int tid = threadIdx.x, ln = tid & 63, wv = tid >> 6;
#pragma unroll
  for (int o = 32; o > 0; o >>= 1) add += __shfl_down(add, o, 64);
  __shared__ int s4[4];
  if (ln == 0) s4[wv] = add;
  __syncthreads();
  if (tid == 0) penpart[blockIdx.x] = s4[0] + s4[1] + s4[2] + s4[3];  // NO atomics
}

// 16 waves: wave w reduces image w's 1024 penpart entries; thread 0 combines all
__global__ __launch_bounds__(1024) void k_final(
    const Accum* __restrict__ acc, const int* __restrict__ penpart,
    float* __restrict__ out) {
  const int tid = threadIdx.x, w = tid >> 6, l = tid & 63;
  int s = 0;
#pragma unroll
  for (int k = 0; k < 16; ++k) s += penpart[(w << 10) + (k << 6) + l];
#pragma unroll
  for (int o = 32; o > 0; o >>= 1) s += __shfl_down(s, o, 64);
  __shared__ int pens[16];
  if (l == 0) pens[w] = s;
  __syncthreads();
  if (tid != 0) return;

  const double ce = acc->ce_num / acc->ce_den;
  double dsum = 0.0;
  for (int k = 0; k < NB * NC; ++k) {
    const double un = acc->sum_probs[k] + (double)acc->cls_cnt[k];
    dsum += (2.0 * acc->inter[k] + 1e-6) / (un + 1e-6);
  }
  const double dice = 1.0 - dsum / (double)(NB * NC);
  const double focal = acc->focal_num / ((double)acc->valid_pix + 1e-6);
  long long tt = 0, pp = 0;
  int nv = 0;
  double pensum = 0.0;
  for (int b = 0; b < NB; ++b) {
    tt += acc->tcount[b];
    pp += acc->pcount[b];
    if (acc->tcount[b] > 0) { nv++; pensum += (double)pens[b]; }
  }
  double pen = 0.0;
  if (nv > 0) pen = pensum / fmax((double)nv * 2.0, 1.0);
  const double sep = (tt > 0 && pp > 0) ? 1.0 /*SEP_PW*/ * pen : 0.0;
  *out = (float)(ce + 0.5 * dice + 0.5 * focal + 0.3 * sep);
}

extern "C" void kernel_launch(void* const* d_in, const int* in_sizes, int n_in,
                              void* d_out, int out_size, void* d_ws, size_t ws_size,
                              hipStream_t stream) {
  (void)in_sizes; (void)n_in; (void)out_size; (void)ws_size;
  const float* pred = (const float*)d_in[0];
  const int* tgt = (const int*)d_in[1];
  const float* cw = (const float*)d_in[2];
  float* out = (float*)d_out;

  char* ws = (char*)d_ws;
  Accum* acc = (Accum*)ws;
  size_t off = 2048;
  Partial* part = (Partial*)(ws + off); off += sizeof(Partial) * NB * 64;  // 98304
  unsigned long long* tmask = (unsigned long long*)(ws + off); off += NPIX / 8;
  unsigned long long* pmask = (unsigned long long*)(ws + off); off += NPIX / 8;
  int* tlab  = (int*)(ws + off); off += (size_t)NPIX * 4;
  int* plab  = (int*)(ws + off); off += (size_t)NPIX * 4;
  int* tconf = (int*)(ws + off); off += (size_t)NPIX * 4;
  int* pconf = (int*)(ws + off); off += (size_t)NPIX * 4;
  int* penpart = (int*)(ws + off); off += (size_t)(NPIX / 256) * 4;  // 64 KB
  // total ~68.4 MiB (R1 proved ws_size >= ~97 MiB)

  hipMemsetAsync(acc, 0, sizeof(Accum), stream);
  hipMemsetAsync(tconf, 0, (size_t)NPIX * 8, stream);  // tconf+pconf contiguous

  const int blocks = NPIX / 256;  // 16384
  k_main<<<NB * 64, 256, 0, stream>>>(pred, tgt, cw, part, tmask, pmask);
  k_reduce<<<1, 1024, 0, stream>>>(part, acc);
  k_local<<<NB * 64 * 2, 256, 0, stream>>>(tmask, pmask, tlab, plab);
  k_border<<<(NB * 2 * 21 * 512) / 256, 256, 0, stream>>>(tlab, plab);
  k_scatter<<<blocks, 256, 0, stream>>>(tmask, pmask, tlab, plab, tconf, pconf);
  k_count<<<blocks, 256, 0, stream>>>(tlab, plab, tconf, pconf, penpart);
  k_final<<<1, 1024, 0, stream>>>(acc, penpart, out);
}

// Round 5
// 233.340 us; speedup vs baseline: 7.5245x; 1.3001x over previous
//
#include <hip/hip_runtime.h>
#include <stdint.h>

// CombinedLoss: weighted CE + dice + focal + connected-component separation.
// B=16, C=3, H=W=512. Output: single f32 scalar.
//
// R5 (vs R4): k_local run-based union-find (horizontal runs merged via bit
// tricks at init; one unite per run/above-run adjacency from run-start lanes
// only); k_scatter CAS-first conf protocol + path compression; k_main float
// inner-loop accumulators + fewer expf; k_count conf-only int4; conf arrays
// zeroed inside k_local (big memset deleted).

#define NB 16
#define NC 3
#define HH 512
#define WW 512
#define HW (HH * WW)          // 262144
#define NPIX (NB * HW)        // 4194304
#define LOG2_HW 18
#define IGNORE_IDX 255
#define SCALE_IDX 2
#define SENT (-1)             // conflict sentinel: >=2 distinct neighbor roots

typedef unsigned long long u64;

struct Accum {
  double ce_num, ce_den, focal_num;
  unsigned long long valid_pix;
  double sum_probs[NB * NC];
  double inter[NB * NC];
  unsigned long long cls_cnt[NB * NC];
  int tcount[NB];
  int pcount[NB];
  int pen[NB];
};

struct Partial {           // 96 B
  double d[9];             // ce_num, ce_den, focal, sp0..2, it0..2
  unsigned int u[6];       // c0, c1, c2, valid, tcnt, pcnt
};

__device__ __forceinline__ double wredd(double v) {
#pragma unroll
  for (int o = 32; o > 0; o >>= 1) v += __shfl_down(v, o, 64);
  return v;
}
__device__ __forceinline__ unsigned int wredu(unsigned int v) {
#pragma unroll
  for (int o = 32; o > 0; o >>= 1) v += __shfl_down(v, o, 64);
  return v;
}

// ---------- fused pointwise losses + mask generation ----------
__global__ __launch_bounds__(256) void k_main(
    const float* __restrict__ pred, const int* __restrict__ tgt,
    const float* __restrict__ cw, Partial* __restrict__ part,
    u64* __restrict__ tmask, u64* __restrict__ pmask) {
  const int bid = blockIdx.x;
  const int b = bid >> 6;        // 64 blocks per batch image
  const int chunk = bid & 63;    // 4096 pixels per block, 16 iters of 256
  const int tid = threadIdx.x;
  const float w0 = cw[0], w1 = cw[1], w2 = cw[2];
  const float* __restrict__ pb = pred + (size_t)b * NC * HW;

  // float accumulators in the hot loop (16 O(1) terms each -> ~1e-7 rel err);
  // converted to double at the wave reduce.
  float ce_num = 0.f, ce_den = 0.f, focal = 0.f;
  float sp0 = 0.f, sp1 = 0.f, sp2 = 0.f, it0 = 0.f, it1 = 0.f, it2 = 0.f;
  unsigned int c0 = 0, c1 = 0, c2 = 0, vc = 0, tc_cnt = 0, pc_cnt = 0;

#pragma unroll 1
  for (int k = 0; k < 16; ++k) {
    const int i = (chunk << 12) + (k << 8) + tid;  // local pixel in image
    const int gp = (b << LOG2_HW) + i;
    const float x0 = pb[i];
    const float x1 = pb[i + HW];
    const float x2 = pb[i + 2 * HW];
    const int t = tgt[gp];

    // log_softmax, jax style: (x - max) - log(sum(exp(x - max)))
    const float m = fmaxf(fmaxf(x0, x1), x2);
    const float e0 = expf(x0 - m), e1 = expf(x1 - m), e2 = expf(x2 - m);
    const float s = e0 + e1 + e2;
    const float ls = logf(s);
    const float inv = 1.0f / s;
    const float p0 = e0 * inv, p1 = e1 * inv, p2 = e2 * inv;

    sp0 += p0; sp1 += p1; sp2 += p2;

    const int tc = (t < 0) ? 0 : ((t > NC - 1) ? NC - 1 : t);
    const float xt = (tc == 0) ? x0 : ((tc == 1) ? x1 : x2);
    const float lpt = (xt - m) - ls;
    const float pt  = (tc == 0) ? p0 : ((tc == 1) ? p1 : p2);
    const float cwt = (tc == 0) ? w0 : ((tc == 1) ? w1 : w2);
    const float valid = (t != IGNORE_IDX) ? 1.0f : 0.0f;
    const float wv = cwt * valid;

    ce_num += wv * (-lpt);
    ce_den += wv;
    const float om = 1.0f - pt;
    focal += cwt * om * om * (-lpt) * valid;
    vc += (t != IGNORE_IDX) ? 1u : 0u;

    if (t >= 0 && t < NC) {  // one_hot(out-of-range) == 0
      if (t == 0)      { it0 += p0; c0++; }
      else if (t == 1) { it1 += p1; c1++; }
      else             { it2 += p2; c2++; }
    }

    // binary fg masks for separation loss (bit-packed via ballot)
    const bool tb = (t == SCALE_IDX);
    const float p2soft = e2 / s;            // IEEE div: keep threshold exact vs R4
    const bool pbit = (p2soft > 0.5f);
    const u64 mt = __ballot(tb);
    const u64 mp = __ballot(pbit);
    if ((tid & 63) == 0) {
      tmask[gp >> 6] = mt;
      pmask[gp >> 6] = mp;
    }
    tc_cnt += tb ? 1u : 0u;
    pc_cnt += pbit ? 1u : 0u;
  }

  // wave -> block reduction; thread0 stores one Partial (NO atomics)
  __shared__ double sd[4][9];
  __shared__ unsigned int si[4][6];
  const int wvid = tid >> 6, ln = tid & 63;
  const double r0 = wredd((double)ce_num), r1 = wredd((double)ce_den),
               r2 = wredd((double)focal),
               r3 = wredd((double)sp0), r4 = wredd((double)sp1),
               r5 = wredd((double)sp2),
               r6 = wredd((double)it0), r7 = wredd((double)it1),
               r8 = wredd((double)it2);
  const unsigned int u0 = wredu(c0), u1 = wredu(c1), u2 = wredu(c2),
                     u3 = wredu(vc), u4 = wredu(tc_cnt), u5 = wredu(pc_cnt);
  if (ln == 0) {
    sd[wvid][0] = r0; sd[wvid][1] = r1; sd[wvid][2] = r2;
    sd[wvid][3] = r3; sd[wvid][4] = r4; sd[wvid][5] = r5;
    sd[wvid][6] = r6; sd[wvid][7] = r7; sd[wvid][8] = r8;
    si[wvid][0] = u0; si[wvid][1] = u1; si[wvid][2] = u2;
    si[wvid][3] = u3; si[wvid][4] = u4; si[wvid][5] = u5;
  }
  __syncthreads();
  if (tid == 0) {
    Partial p;
    for (int q = 0; q < 9; ++q) p.d[q] = sd[0][q] + sd[1][q] + sd[2][q] + sd[3][q];
    for (int q = 0; q < 6; ++q) p.u[q] = si[0][q] + si[1][q] + si[2][q] + si[3][q];
    part[bid] = p;
  }
}

// ---------- single-block partial reduction (16 waves = 16 images) ----------
__global__ __launch_bounds__(1024) void k_reduce(
    const Partial* __restrict__ part, Accum* __restrict__ acc) {
  const int tid = threadIdx.x;
  const int w = tid >> 6, l = tid & 63;      // wave w owns image w, lane l = chunk l
  const Partial p = part[w * 64 + l];
  double d[9];
  unsigned int u[6];
#pragma unroll
  for (int q = 0; q < 9; ++q) d[q] = wredd(p.d[q]);
#pragma unroll
  for (int q = 0; q < 6; ++q) u[q] = wredu(p.u[q]);

  __shared__ double gsd[16][3];
  __shared__ unsigned int gsu[16];
  if (l == 0) {
    acc->sum_probs[w * NC + 0] = d[3];
    acc->sum_probs[w * NC + 1] = d[4];
    acc->sum_probs[w * NC + 2] = d[5];
    acc->inter[w * NC + 0] = d[6];
    acc->inter[w * NC + 1] = d[7];
    acc->inter[w * NC + 2] = d[8];
    acc->cls_cnt[w * NC + 0] = (unsigned long long)u[0];
    acc->cls_cnt[w * NC + 1] = (unsigned long long)u[1];
    acc->cls_cnt[w * NC + 2] = (unsigned long long)u[2];
    acc->tcount[w] = (int)u[4];
    acc->pcount[w] = (int)u[5];
    gsd[w][0] = d[0]; gsd[w][1] = d[1]; gsd[w][2] = d[2];
    gsu[w] = u[3];
  }
  __syncthreads();
  if (tid == 0) {
    double a0 = 0, a1 = 0, a2 = 0;
    unsigned long long av = 0;
    for (int q = 0; q < 16; ++q) {
      a0 += gsd[q][0]; a1 += gsd[q][1]; a2 += gsd[q][2]; av += gsu[q];
    }
    acc->ce_num = a0; acc->ce_den = a1; acc->focal_num = a2; acc->valid_pix = av;
  }
}

// ---------- LDS union-find (tile-local) ----------
__device__ __forceinline__ int find_lds(volatile int* par, int x) {
  int p = par[x];
  while (p != x) { x = p; p = par[x]; }
  return x;
}
__device__ __forceinline__ void unite_lds(int* par, int a, int b) {
  int la = find_lds(par, a);
  int lb = find_lds(par, b);
  while (la != lb) {
    if (la < lb) { int t = la; la = lb; lb = t; }  // la > lb
    const int old = atomicMin(&par[la], lb);
    if (old == la) break;
    la = old;
  }
}

// one block = one (image, mask, 64x64 tile); run-based CC in LDS.
// Also zero-initializes this tile's conf slots (replaces a 33.5 MB memset).
__global__ __launch_bounds__(256) void k_local(
    const u64* __restrict__ tmask, const u64* __restrict__ pmask,
    int* __restrict__ tlab, int* __restrict__ plab,
    int* __restrict__ tconf, int* __restrict__ pconf) {
  const int idx = blockIdx.x;
  const int img = idx >> 7;
  const int rest = idx & 127;
  const int maskid = rest >> 6;
  const int tile = rest & 63;
  const int ty = tile >> 3, tx = tile & 7;
  const u64* __restrict__ mg = (maskid ? pmask : tmask) + (size_t)img * (HW / 64);
  int* __restrict__ lab  = (maskid ? plab : tlab)   + ((size_t)img << LOG2_HW);
  int* __restrict__ conf = (maskid ? pconf : tconf) + ((size_t)img << LOG2_HW);
  const int tid = threadIdx.x;
  const int lane = tid & 63, wv = tid >> 6;

  __shared__ int par[4096];
  __shared__ u64 mw[64];
  if (tid < 64) mw[tid] = mg[(ty * 64 + tid) * 8 + tx];  // tile row = 1 u64 word
  __syncthreads();

  // Phase A: init with run-start labels (merges ALL horizontal edges for free)
#pragma unroll 1
  for (int k = 0; k < 16; ++k) {
    const int y = (k << 2) + wv;             // wave wv owns rows wv, wv+4, ...
    const u64 w = mw[y];
    int v = -1;
    if ((w >> lane) & 1ull) {
      const u64 sa = w & ~(w << 1);                       // run-start bits
      const u64 le = sa & (~0ull >> (63 - lane));         // starts at <= lane
      v = (y << 6) + (63 - __clzll(le));                  // my run's start
    }
    par[(y << 6) + lane] = v;
  }
  __syncthreads();

  // Phase B: run-start lanes unite with each distinct above-run overlapping
  // the window [runstart-1, runend+1] (covers N/NW/NE, deduped per run pair).
#pragma unroll 1
  for (int k = 0; k < 16; ++k) {
    const int y = (k << 2) + wv;
    if (y == 0) continue;
    const u64 w = mw[y];
    if (!((w >> lane) & 1ull)) continue;
    if (lane > 0 && ((w >> (lane - 1)) & 1ull)) continue;  // not a run start
    const u64 z = w >> lane;
    const u64 crun = (z & ~(z + 1)) << lane;               // bits of my run
    const u64 win = crun | (crun << 1) | (crun >> 1);
    const u64 a = mw[y - 1];
    u64 aw = a & win;
    const u64 sa = a & ~(a << 1);
    const int me = (y << 6) + lane;
    while (aw) {
      const int p = (int)(__ffsll((long long)aw) - 1);
      const u64 le = sa & (~0ull >> (63 - p));
      const int rs = 63 - __clzll(le);                     // above run's start
      unite_lds(par, me, ((y - 1) << 6) + rs);
      const u64 za = a >> p;
      aw &= ~((za & ~(za + 1)) << p);                      // clear that run
    }
  }
  __syncthreads();

  // Phase C: write global labels (pixel -> global idx of tile root) + conf=0
#pragma unroll 1
  for (int k = 0; k < 16; ++k) {
    const int li = (k << 8) + tid;
    const int y = li >> 6, x = li & 63;
    int out = -1;
    if (par[li] >= 0) {
      int r = par[li], p = par[r];
      while (p != r) { r = p; p = par[r]; }  // static after barrier
      out = (ty * 64 + (r >> 6)) * WW + tx * 64 + (r & 63);
    }
    const int gi = (ty * 64 + y) * WW + tx * 64 + x;
    lab[gi] = out;
    conf[gi] = 0;
  }
}

// ---------- global union-find (border edges only) ----------
__device__ __forceinline__ int lread(int* p) {
  return __hip_atomic_load(p, __ATOMIC_RELAXED, __HIP_MEMORY_SCOPE_AGENT);
}
__device__ __forceinline__ int findroot(int* L, int x) {
  int p = lread(&L[x]);
  while (p != x) { x = p; p = lread(&L[x]); }
  return x;
}
__device__ __forceinline__ void unite(int* L, int a, int b) {
  int la = findroot(L, a);
  int lb = findroot(L, b);
  while (la != lb) {
    if (la < lb) { int t = la; la = lb; lb = t; }
    const int old = atomicMin(&L[la], lb);
    if (old == la) break;
    la = old;
  }
}

// 21 lines per (img, mask): 7 horiz rows y=64k; 7 vert cols x=64k; 7 cols x=64k-1
__global__ __launch_bounds__(256) void k_border(int* __restrict__ tlab, int* __restrict__ plab) {
  const int t = blockIdx.x * 256 + threadIdx.x;  // 344064 total
  const int pos = t & 511;
  const int rest = t >> 9;          // 0..671
  const int line = rest % 21;
  const int rest2 = rest / 21;      // 0..31
  const int maskid = rest2 & 1;
  const int img = rest2 >> 1;
  int* __restrict__ lab = (maskid ? plab : tlab) + ((size_t)img << LOG2_HW);
  if (line < 7) {                        // horizontal border row
    const int i = (((line + 1) << 6) * WW) + pos;
    if (lab[i] < 0) return;
    if (lab[i - WW] >= 0) unite(lab, i, i - WW);                      // N
    if (pos > 0 && lab[i - WW - 1] >= 0) unite(lab, i, i - WW - 1);   // NW
    if (pos < WW - 1 && lab[i - WW + 1] >= 0) unite(lab, i, i - WW + 1);  // NE
  } else if (line < 14) {                // vertical border, left col x=64k
    const int i = pos * WW + ((line - 6) << 6);
    if (lab[i] < 0) return;
    if (lab[i - 1] >= 0) unite(lab, i, i - 1);                        // W
    if (pos > 0 && lab[i - WW - 1] >= 0) unite(lab, i, i - WW - 1);   // NW
  } else {                               // vertical border, right col x=64k-1
    if (pos == 0) return;
    const int i = pos * WW + (((line - 13) << 6) - 1);
    if (lab[i] < 0) return;
    if (lab[i - WW + 1] >= 0) unite(lab, i, i - WW + 1);              // NE
  }
}

// ---------- scatter: CAS-first monotone conflict slot 0 -> val+1 -> SENT ----
__device__ __forceinline__ void conf_update(int* __restrict__ conf, int key, int val) {
  const int tag = val + 1;  // val < 2^18, so tag > 0 and != SENT
  const int old = atomicCAS(&conf[key], 0, tag);
  if (old == 0 || old == tag || old == SENT) return;
  atomicExch(&conf[key], SENT);  // second distinct tag -> conflict
}

// chase to root with path compression (forest static; all writers store the
// same final root, so the plain-store race is benign)
__device__ __forceinline__ int chase_compress(int* __restrict__ L, int i) {
  const int p0 = L[i];
  int r = p0, p = L[r];
  if (p == r) return r;
  do { r = p; p = L[r]; } while (p != r);
  L[p0] = r;
  return r;
}

__global__ __launch_bounds__(256) void k_scatter(
    const u64* __restrict__ tmask, const u64* __restrict__ pmask,
    int* __restrict__ tlab, int* __restrict__ plab,
    int* __restrict__ tconf, int* __restrict__ pconf) {
  const int gt = blockIdx.x * 256 + threadIdx.x;
  const int bb = gt >> LOG2_HW;
  const int i = gt & (HW - 1);
  const size_t base = (size_t)bb << LOG2_HW;
  const int lane = threadIdx.x & 63;
  // whole wave shares one mask word (broadcast load)
  const u64 tw = tmask[gt >> 6];
  const u64 pw = pmask[gt >> 6];
  if ((tw & pw) == 0) return;            // wave-uniform early out
  const bool act = ((tw >> lane) & 1ull) & ((pw >> lane) & 1ull);
  if (!act) return;
  const int rt = chase_compress(tlab + base, i);
  const int rp = chase_compress(plab + base, i);
  conf_update(tconf + base, rt, rp);
  conf_update(pconf + base, rp, rt);
}

// conf slots are only ever written at true roots, so counting SENT entries
// needs NO label reads.
__global__ __launch_bounds__(256) void k_count(
    const int4* __restrict__ tconf4, const int4* __restrict__ pconf4,
    int* __restrict__ penpart) {
  const int gt = blockIdx.x * 256 + threadIdx.x;   // over NPIX/4
  const int4 a = tconf4[gt];
  const int4 b = pconf4[gt];
  int add = (a.x == SENT) + (a.y == SENT) + (a.z == SENT) + (a.w == SENT)
          + (b.x == SENT) + (b.y == SENT) + (b.z == SENT) + (b.w == SENT);
  const int tid = threadIdx.x, ln = tid & 63, wv = tid >> 6;
#pragma unroll
  for (int o = 32; o > 0; o >>= 1) add += __shfl_down(add, o, 64);
  __shared__ int s4[4];
  if (ln == 0) s4[wv] = add;
  __syncthreads();
  if (tid == 0) penpart[blockIdx.x] = s4[0] + s4[1] + s4[2] + s4[3];  // NO atomics
}

// 16 waves: wave w reduces image w's 256 penpart entries; thread 0 combines all
__global__ __launch_bounds__(1024) void k_final(
    const Accum* __restrict__ acc, const int* __restrict__ penpart,
    float* __restrict__ out) {
  const int tid = threadIdx.x, w = tid >> 6, l = tid & 63;
  int s = 0;
#pragma unroll
  for (int k = 0; k < 4; ++k) s += penpart[(w << 8) + (k << 6) + l];
#pragma unroll
  for (int o = 32; o > 0; o >>= 1) s += __shfl_down(s, o, 64);
  __shared__ int pens[16];
  if (l == 0) pens[w] = s;
  __syncthreads();
  if (tid != 0) return;

  const double ce = acc->ce_num / acc->ce_den;
  double dsum = 0.0;
  for (int k = 0; k < NB * NC; ++k) {
    const double un = acc->sum_probs[k] + (double)acc->cls_cnt[k];
    dsum += (2.0 * acc->inter[k] + 1e-6) / (un + 1e-6);
  }
  const double dice = 1.0 - dsum / (double)(NB * NC);
  const double focal = acc->focal_num / ((double)acc->valid_pix + 1e-6);
  long long tt = 0, pp = 0;
  int nv = 0;
  double pensum = 0.0;
  for (int b = 0; b < NB; ++b) {
    tt += acc->tcount[b];
    pp += acc->pcount[b];
    if (acc->tcount[b] > 0) { nv++; pensum += (double)pens[b]; }
  }
  double pen = 0.0;
  if (nv > 0) pen = pensum / fmax((double)nv * 2.0, 1.0);
  const double sep = (tt > 0 && pp > 0) ? 1.0 /*SEP_PW*/ * pen : 0.0;
  *out = (float)(ce + 0.5 * dice + 0.5 * focal + 0.3 * sep);
}

extern "C" void kernel_launch(void* const* d_in, const int* in_sizes, int n_in,
                              void* d_out, int out_size, void* d_ws, size_t ws_size,
                              hipStream_t stream) {
  (void)in_sizes; (void)n_in; (void)out_size; (void)ws_size;
  const float* pred = (const float*)d_in[0];
  const int* tgt = (const int*)d_in[1];
  const float* cw = (const float*)d_in[2];
  float* out = (float*)d_out;

  char* ws = (char*)d_ws;
  Accum* acc = (Accum*)ws;
  size_t off = 2048;
  Partial* part = (Partial*)(ws + off); off += sizeof(Partial) * NB * 64;  // 98304
  u64* tmask = (u64*)(ws + off); off += NPIX / 8;
  u64* pmask = (u64*)(ws + off); off += NPIX / 8;
  int* tlab  = (int*)(ws + off); off += (size_t)NPIX * 4;
  int* plab  = (int*)(ws + off); off += (size_t)NPIX * 4;
  int* tconf = (int*)(ws + off); off += (size_t)NPIX * 4;
  int* pconf = (int*)(ws + off); off += (size_t)NPIX * 4;
  int* penpart = (int*)(ws + off); off += (size_t)(NPIX / 1024) * 4;  // 16 KB
  // total ~68.4 MiB (R1 proved ws_size >= ~97 MiB)

  hipMemsetAsync(acc, 0, sizeof(Accum), stream);

  k_main<<<NB * 64, 256, 0, stream>>>(pred, tgt, cw, part, tmask, pmask);
  k_reduce<<<1, 1024, 0, stream>>>(part, acc);
  k_local<<<NB * 64 * 2, 256, 0, stream>>>(tmask, pmask, tlab, plab, tconf, pconf);
  k_border<<<(NB * 2 * 21 * 512) / 256, 256, 0, stream>>>(tlab, plab);
  k_scatter<<<NPIX / 256, 256, 0, stream>>>(tmask, pmask, tlab, plab, tconf, pconf);
  k_count<<<NPIX / 1024, 256, 0, stream>>>((const int4*)tconf, (const int4*)pconf, penpart);
  k_final<<<1, 1024, 0, stream>>>(acc, penpart, out);
}